// Round 4
// baseline (85.382 us; speedup 1.0000x reference)
//
#include <hip/hip_runtime.h>
#include <hip/hip_cooperative_groups.h>
#include <hip/hip_bf16.h>
#include <float.h>

namespace cg = cooperative_groups;

// VQ bottleneck, single cooperative dispatch.
// encoded: (2048, 256) f32, emb: (1, 256, 512) f32.
// out: latent (2048*256) f32 ++ loss (1) f32.
//
// d2 = fl(fl(x-c)^2) is monotone in |x-c| per side => argmin is one of the two
// sorted-order neighbors of x. Sorted (val, original-idx) pairs reproduce
// np.argmin's first-index tie-break exactly (exact-midpoint case).
//
// Phase 1: block b sorts codebook dim b  -> ws tables
// Phase 2: block b = (dtile, stile) does coalesced binary-search quantize
// Phase 3: block 0 reduces loss partials (fixed order, deterministic)

#define NSAMP 2048
#define NDIM  256
#define NCODE 512
#define DT    16
#define ST    128
#define CBS   516   // 512+4 pad: 16B-aligned, conflict-free uniform probes

// ---- ws layout ----
#define WS_VAL_OFF  0
#define WS_IDX_OFF  (NDIM * NCODE * 4)                  // 512 KB
#define WS_LOSS_OFF (WS_IDX_OFF + NDIM * NCODE * 2)     // 768 KB
#define WS_NEEDED   (WS_LOSS_OFF + 4096)

__global__ __launch_bounds__(512)
void vq_onepass(const float* __restrict__ enc,
                const float* __restrict__ emb,
                float* __restrict__ out,
                float* __restrict__ wsVal,
                unsigned short* __restrict__ wsIdx,
                float* __restrict__ wsLoss)
{
    __shared__ float          sv[NCODE];
    __shared__ int            si[NCODE];
    __shared__ float          cbv[DT][CBS];
    __shared__ unsigned short cbi[DT][CBS];
    __shared__ float          red[8];

    const int tid = threadIdx.x;
    const int b   = blockIdx.x;
    cg::grid_group grid = cg::this_grid();

    // ================= phase 1: bitonic sort of codebook dim b =================
    {
        float v  = emb[b * NCODE + tid];
        int  idx = tid;
        for (int k = 2; k <= NCODE; k <<= 1) {
            for (int j = k >> 1; j > 0; j >>= 1) {
                float v2; int i2;
                if (j < 64) {
                    v2 = __shfl_xor(v, j, 64);
                    i2 = __shfl_xor(idx, j, 64);
                } else {
                    sv[tid] = v; si[tid] = idx;
                    __syncthreads();
                    v2 = sv[tid ^ j]; i2 = si[tid ^ j];
                    __syncthreads();
                }
                bool less  = (v < v2) || (v == v2 && idx < i2);  // total order
                bool lower = (tid & j) == 0;
                bool up    = (tid & k) == 0;
                if ((lower == up) != less) { v = v2; idx = i2; }
            }
        }
        wsVal[b * NCODE + tid] = v;
        wsIdx[b * NCODE + tid] = (unsigned short)idx;
    }

    grid.sync();

    // ================= phase 2: coalesced binary-search quantize =================
    const int dtile = b & (NDIM / DT - 1);
    const int stile = b >> 4;
    const int d0    = dtile * DT;
    const int n0    = stile * ST;

    {
        const float4* src = reinterpret_cast<const float4*>(wsVal + d0 * NCODE);
        for (int i4 = tid; i4 < DT * NCODE / 4; i4 += 512) {
            float4 q = src[i4];
            int i = i4 * 4, dl2 = i >> 9, pos = i & (NCODE - 1);
            *reinterpret_cast<float4*>(&cbv[dl2][pos]) = q;
        }
        const uint2* srci = reinterpret_cast<const uint2*>(wsIdx + d0 * NCODE);
        for (int i4 = tid; i4 < DT * NCODE / 4; i4 += 512) {
            uint2 q = srci[i4];
            int i = i4 * 4, dl2 = i >> 9, pos = i & (NCODE - 1);
            *reinterpret_cast<uint2*>(&cbi[dl2][pos]) = q;
        }
    }
    __syncthreads();

    const int dl = tid & (DT - 1);
    const int rg = tid >> 4;                  // 0..31
    const float*          vrow = cbv[dl];
    const unsigned short* irow = cbi[dl];

    float x[4]; int gi[4];
#pragma unroll
    for (int r = 0; r < 4; ++r) {
        int n = n0 + rg + 32 * r;
        gi[r] = n * NDIM + d0 + dl;
        x[r]  = enc[gi[r]];
    }

    int p[4] = {0, 0, 0, 0};
#pragma unroll
    for (int s = NCODE / 2; s > 0; s >>= 1) {
#pragma unroll
        for (int r = 0; r < 4; ++r)
            if (vrow[p[r] + s - 1] < x[r]) p[r] += s;
    }

    float acc = 0.0f;
#pragma unroll
    for (int r = 0; r < 4; ++r) {
        int pp = p[r];
        if (vrow[pp] < x[r]) ++pp;            // count==512 fixup
        float d2l = FLT_MAX, d2r = FLT_MAX, vl = 0.0f, vr = 0.0f;
        int il = 0x7fffffff, ir = 0x7fffffff;
        if (pp > 0)     { vl = vrow[pp - 1]; il = irow[pp - 1]; float t = x[r] - vl; d2l = t * t; }
        if (pp < NCODE) { vr = vrow[pp];     ir = irow[pp];     float t = x[r] - vr; d2r = t * t; }
        out[gi[r]] = (d2l < d2r) ? vl : (d2r < d2l) ? vr : ((il < ir) ? vl : vr);
        acc += fminf(d2l, d2r);
    }

#pragma unroll
    for (int off = 32; off > 0; off >>= 1)
        acc += __shfl_down(acc, off, 64);
    if ((tid & 63) == 0) red[tid >> 6] = acc;
    __syncthreads();
    if (tid == 0) {
        float s = 0.0f;
#pragma unroll
        for (int w = 0; w < 8; ++w) s += red[w];
        wsLoss[b] = s;
    }

    grid.sync();

    // ================= phase 3: block 0 reduces 256 partials =================
    if (b == 0 && tid < NDIM) {
        float a2 = wsLoss[tid];
#pragma unroll
        for (int off = 32; off > 0; off >>= 1)
            a2 += __shfl_down(a2, off, 64);
        if ((tid & 63) == 0) red[tid >> 6] = a2;
    }
    __syncthreads();
    if (b == 0 && tid == 0)
        out[NSAMP * NDIM] = 2.0f * (red[0] + red[1] + red[2] + red[3]);
}

// ======================= fallback: proven R2 3-kernel path =======================
__global__ __launch_bounds__(512)
void vq_sort(const float* __restrict__ emb,
             float* __restrict__ wsVal,
             unsigned short* __restrict__ wsIdx)
{
    __shared__ float sv[NCODE];
    __shared__ int   si[NCODE];
    const int tid = threadIdx.x;
    const int d   = blockIdx.x;
    float v  = emb[d * NCODE + tid];
    int  idx = tid;
    for (int k = 2; k <= NCODE; k <<= 1) {
        for (int j = k >> 1; j > 0; j >>= 1) {
            float v2; int i2;
            if (j < 64) {
                v2 = __shfl_xor(v, j, 64);
                i2 = __shfl_xor(idx, j, 64);
            } else {
                sv[tid] = v; si[tid] = idx;
                __syncthreads();
                v2 = sv[tid ^ j]; i2 = si[tid ^ j];
                __syncthreads();
            }
            bool less  = (v < v2) || (v == v2 && idx < i2);
            bool lower = (tid & j) == 0;
            bool up    = (tid & k) == 0;
            if ((lower == up) != less) { v = v2; idx = i2; }
        }
    }
    wsVal[d * NCODE + tid] = v;
    wsIdx[d * NCODE + tid] = (unsigned short)idx;
}

__global__ __launch_bounds__(256)
void vq_search(const float* __restrict__ enc,
               const float* __restrict__ wsVal,
               const unsigned short* __restrict__ wsIdx,
               float* __restrict__ out,
               float* __restrict__ wsLoss)
{
    __shared__ float          cbv[DT][CBS];
    __shared__ unsigned short cbi[DT][CBS];
    __shared__ float red[4];

    const int tid   = threadIdx.x;
    const int bx    = blockIdx.x;
    const int dtile = bx & (NDIM / DT - 1);
    const int stile = bx >> 4;
    const int d0    = dtile * DT;
    const int n0    = stile * ST;

    {
        const float4* src = reinterpret_cast<const float4*>(wsVal + d0 * NCODE);
        for (int i4 = tid; i4 < DT * NCODE / 4; i4 += 256) {
            float4 q = src[i4];
            int i = i4 * 4, dl2 = i >> 9, pos = i & (NCODE - 1);
            *reinterpret_cast<float4*>(&cbv[dl2][pos]) = q;
        }
        const uint2* srci = reinterpret_cast<const uint2*>(wsIdx + d0 * NCODE);
        for (int i4 = tid; i4 < DT * NCODE / 4; i4 += 256) {
            uint2 q = srci[i4];
            int i = i4 * 4, dl2 = i >> 9, pos = i & (NCODE - 1);
            *reinterpret_cast<uint2*>(&cbi[dl2][pos]) = q;
        }
    }
    __syncthreads();

    const int dl = tid & (DT - 1);
    const float*          vrow = cbv[dl];
    const unsigned short* irow = cbi[dl];

    float x[8]; int gidx[8];
#pragma unroll
    for (int r = 0; r < 8; ++r) {
        int nl = (tid >> 4) + 16 * r;
        gidx[r] = (n0 + nl) * NDIM + d0 + dl;
        x[r] = enc[gidx[r]];
    }

    int p[8];
#pragma unroll
    for (int r = 0; r < 8; ++r) p[r] = 0;
#pragma unroll
    for (int s = NCODE / 2; s > 0; s >>= 1) {
#pragma unroll
        for (int r = 0; r < 8; ++r)
            if (vrow[p[r] + s - 1] < x[r]) p[r] += s;
    }

    float acc = 0.0f;
#pragma unroll
    for (int r = 0; r < 8; ++r) {
        int pp = p[r];
        if (vrow[pp] < x[r]) ++pp;
        float d2l = FLT_MAX, d2r = FLT_MAX, vl = 0.0f, vr = 0.0f;
        int il = 0x7fffffff, ir = 0x7fffffff;
        if (pp > 0)     { vl = vrow[pp - 1]; il = irow[pp - 1]; float t = x[r] - vl; d2l = t * t; }
        if (pp < NCODE) { vr = vrow[pp];     ir = irow[pp];     float t = x[r] - vr; d2r = t * t; }
        out[gidx[r]] = (d2l < d2r) ? vl : (d2r < d2l) ? vr : ((il < ir) ? vl : vr);
        acc += fminf(d2l, d2r);
    }

#pragma unroll
    for (int off = 32; off > 0; off >>= 1)
        acc += __shfl_down(acc, off, 64);
    if ((tid & 63) == 0) red[tid >> 6] = acc;
    __syncthreads();
    if (tid == 0)
        wsLoss[bx] = red[0] + red[1] + red[2] + red[3];
}

__global__ __launch_bounds__(256)
void vq_final(const float* __restrict__ wsLoss, float* __restrict__ out)
{
    __shared__ float red[4];
    const int tid = threadIdx.x;
    float acc = wsLoss[tid];
#pragma unroll
    for (int off = 32; off > 0; off >>= 1)
        acc += __shfl_down(acc, off, 64);
    if ((tid & 63) == 0) red[tid >> 6] = acc;
    __syncthreads();
    if (tid == 0)
        out[NSAMP * NDIM] = 2.0f * (red[0] + red[1] + red[2] + red[3]);
}

extern "C" void kernel_launch(void* const* d_in, const int* in_sizes, int n_in,
                              void* d_out, int out_size, void* d_ws, size_t ws_size,
                              hipStream_t stream)
{
    const float* enc = (const float*)d_in[0];   // (2048, 256)
    const float* emb = (const float*)d_in[1];   // (1, 256, 512)
    float* out = (float*)d_out;

    char* ws = (char*)d_ws;
    float*          wsVal  = (float*)(ws + WS_VAL_OFF);
    unsigned short* wsIdx  = (unsigned short*)(ws + WS_IDX_OFF);
    float*          wsLoss = (float*)(ws + WS_LOSS_OFF);

    bool coop_ok = false;
    if (ws_size >= (size_t)WS_NEEDED) {
        int dev = 0;
        (void)hipGetDevice(&dev);
        int attr = 0;
        (void)hipDeviceGetAttribute(&attr, hipDeviceAttributeCooperativeLaunch, dev);
        if (attr) {
            void* args[] = {(void*)&enc, (void*)&emb, (void*)&out,
                            (void*)&wsVal, (void*)&wsIdx, (void*)&wsLoss};
            hipError_t e = hipLaunchCooperativeKernel((const void*)vq_onepass,
                                                      dim3(NDIM), dim3(512),
                                                      args, 0, stream);
            coop_ok = (e == hipSuccess);
        }
    }

    if (!coop_ok && ws_size >= (size_t)WS_NEEDED) {
        vq_sort  <<<NDIM, 512, 0, stream>>>(emb, wsVal, wsIdx);
        vq_search<<<(NSAMP / ST) * (NDIM / DT), 256, 0, stream>>>(enc, wsVal, wsIdx, out, wsLoss);
        vq_final <<<1, NDIM, 0, stream>>>(wsLoss, out);
    }
}

// Round 5
// 37.094 us; speedup vs baseline: 2.3017x; 2.3017x over previous
//
#include <hip/hip_runtime.h>
#include <hip/hip_bf16.h>
#include <float.h>

// VQ bottleneck, single fused kernel (+4B memset for the last-block counter).
// encoded: (2048, 256) f32, emb: (1, 256, 512) f32.
// out: latent (2048*256) f32 ++ loss (1) f32.
//
// Block b handles dim b entirely: bitonic-sort the 512 codebook values for
// dim b in registers/LDS (shfl for j<64 stages), then binary-search all 2048
// samples of column b. d2 = fl(fl(x-c)^2) is monotone in |x-c| per side, so
// the argmin is one of the two sorted-order neighbors; carrying original
// indices reproduces np.argmin's first-index tie-break exactly.
// Loss: per-block partial -> ws, __threadfence + atomicAdd counter; the last
// block sums the 256 partials in fixed order (deterministic) -> out[N].
// Counter is zeroed every call by a 4-byte hipMemsetAsync (graph memset node).

#define NSAMP 2048
#define NDIM  256
#define NCODE 512

__global__ __launch_bounds__(512)
void vq_fused(const float* __restrict__ enc,
              const float* __restrict__ emb,
              float* __restrict__ out,
              unsigned int* __restrict__ cnt,
              float* __restrict__ wsLoss)
{
    __shared__ float sv[NCODE];
    __shared__ int   si[NCODE];
    __shared__ float red[8];
    __shared__ int   islast;

    const int tid = threadIdx.x;
    const int b   = blockIdx.x;          // one block per dimension

    // ================= phase 1: bitonic sort of codebook dim b =================
    {
        float v  = emb[b * NCODE + tid];
        int  idx = tid;
        for (int k = 2; k <= NCODE; k <<= 1) {
            for (int j = k >> 1; j > 0; j >>= 1) {
                float v2; int i2;
                if (j < 64) {
                    v2 = __shfl_xor(v, j, 64);
                    i2 = __shfl_xor(idx, j, 64);
                } else {
                    sv[tid] = v; si[tid] = idx;
                    __syncthreads();
                    v2 = sv[tid ^ j]; i2 = si[tid ^ j];
                    __syncthreads();
                }
                // total order (val, idx): handles duplicate values exactly
                bool less  = (v < v2) || (v == v2 && idx < i2);
                bool lower = (tid & j) == 0;
                bool up    = (tid & k) == 0;   // k==512 stage: ascending merge
                if ((lower == up) != less) { v = v2; idx = i2; }
            }
        }
        sv[tid] = v;          // sorted values stay in LDS
        si[tid] = idx;        // original indices for tie-break
    }
    __syncthreads();

    // ================= phase 2: 4 interleaved binary searches =================
    float x[4];
#pragma unroll
    for (int r = 0; r < 4; ++r)
        x[r] = enc[(tid + 512 * r) * NDIM + b];

    int p[4] = {0, 0, 0, 0};
#pragma unroll
    for (int s = NCODE / 2; s > 0; s >>= 1) {
#pragma unroll
        for (int r = 0; r < 4; ++r)
            if (sv[p[r] + s - 1] < x[r]) p[r] += s;   // p = #(val < x), capped 511
    }

    float acc = 0.0f;
#pragma unroll
    for (int r = 0; r < 4; ++r) {
        int pp = p[r];
        if (sv[pp] < x[r]) ++pp;                      // count==512 fixup
        float d2l = FLT_MAX, d2r = FLT_MAX, vl = 0.0f, vr = 0.0f;
        int il = 0x7fffffff, ir = 0x7fffffff;
        if (pp > 0)     { vl = sv[pp - 1]; il = si[pp - 1]; float t = x[r] - vl; d2l = t * t; }
        if (pp < NCODE) { vr = sv[pp];     ir = si[pp];     float t = x[r] - vr; d2r = t * t; }
        out[(tid + 512 * r) * NDIM + b] =
            (d2l < d2r) ? vl : (d2r < d2l) ? vr : ((il < ir) ? vl : vr);
        acc += fminf(d2l, d2r);
    }

    // ================= phase 3: block partial + last-block reduce =================
#pragma unroll
    for (int off = 32; off > 0; off >>= 1)
        acc += __shfl_down(acc, off, 64);
    if ((tid & 63) == 0) red[tid >> 6] = acc;
    __syncthreads();

    if (tid == 0) {
        float s = 0.0f;
#pragma unroll
        for (int w = 0; w < 8; ++w) s += red[w];
        wsLoss[b] = s;
        __threadfence();                               // publish partial
        unsigned int old = atomicAdd(cnt, 1u);         // device-scope
        islast = (old == (unsigned int)(NDIM - 1));
    }
    __syncthreads();

    if (islast) {
        __threadfence();                               // acquire all partials
        if (tid < NDIM) {
            const volatile float* wl = wsLoss;
            float a2 = wl[tid];
#pragma unroll
            for (int off = 32; off > 0; off >>= 1)
                a2 += __shfl_down(a2, off, 64);
            if ((tid & 63) == 0) red[tid >> 6] = a2;   // red[0..3], fixed order
        }
        __syncthreads();
        if (tid == 0)
            out[NSAMP * NDIM] = 2.0f * (red[0] + red[1] + red[2] + red[3]);
    }
}

extern "C" void kernel_launch(void* const* d_in, const int* in_sizes, int n_in,
                              void* d_out, int out_size, void* d_ws, size_t ws_size,
                              hipStream_t stream)
{
    const float* enc = (const float*)d_in[0];   // (2048, 256)
    const float* emb = (const float*)d_in[1];   // (1, 256, 512)
    float* out = (float*)d_out;                 // latent ++ loss

    unsigned int* cnt    = (unsigned int*)d_ws;             // 4B counter
    float*        wsLoss = (float*)((char*)d_ws + 64);      // 256 partials

    // zero the counter every call (ws is poisoned once and never re-poisoned;
    // async memset graph-captures as a memset node)
    hipMemsetAsync(cnt, 0, sizeof(unsigned int), stream);

    vq_fused<<<NDIM, 512, 0, stream>>>(enc, emb, out, cnt, wsLoss);
}

// Round 6
// 26.067 us; speedup vs baseline: 3.2755x; 1.4231x over previous
//
#include <hip/hip_runtime.h>
#include <hip/hip_bf16.h>
#include <float.h>

// VQ bottleneck, 2 dispatches, no memset node (tiny graph memsets cost ~39us!).
// encoded: (2048, 256) f32, emb: (1, 256, 512) f32.
// out: latent (2048*256) f32 ++ loss (1) f32.
//
// Kernel A: block b bitonic-sorts codebook dim b -> (val,idx) tables in ws;
//           thread (0,0) zeroes the last-block counter (visible to kernel B
//           via kernel-boundary ordering; replaces the pathological memset).
// Kernel B: coalesced tiled binary-search quantize + loss partials +
//           last-block deterministic reduce (threadfence + atomicAdd counter).
//
// d2 = fl(fl(x-c)^2) is monotone in |x-c| per side => argmin is one of the two
// sorted-order neighbors of x; carrying original indices reproduces np.argmin's
// first-index tie-break exactly (exact-midpoint / duplicate-value cases).

#define NSAMP 2048
#define NDIM  256
#define NCODE 512
#define DT    16
#define ST    128
#define CBS   516   // 512+4 pad: 16B-aligned rows, conflict-free probes

// ---- ws layout ----
#define WS_CNT_OFF  0                                    // 4B counter (own line)
#define WS_LOSS_OFF 64                                   // 256 partials
#define WS_VAL_OFF  4096                                 // 512 KB sorted values
#define WS_IDX_OFF  (WS_VAL_OFF + NDIM * NCODE * 4)      // 256 KB sorted indices
#define WS_NEEDED   (WS_IDX_OFF + NDIM * NCODE * 2)

// ================= kernel A: per-dim bitonic sort + counter init =================
__global__ __launch_bounds__(512)
void vq_sort_init(const float* __restrict__ emb,
                  float* __restrict__ wsVal,
                  unsigned short* __restrict__ wsIdx,
                  unsigned int* __restrict__ cnt)
{
    __shared__ float sv[NCODE];
    __shared__ int   si[NCODE];

    const int tid = threadIdx.x;
    const int d   = blockIdx.x;

    if (d == 0 && tid == 0) *cnt = 0u;     // replaces 39us memset node

    float v  = emb[d * NCODE + tid];
    int  idx = tid;

    for (int k = 2; k <= NCODE; k <<= 1) {
        for (int j = k >> 1; j > 0; j >>= 1) {
            float v2; int i2;
            if (j < 64) {
                v2 = __shfl_xor(v, j, 64);
                i2 = __shfl_xor(idx, j, 64);
            } else {
                sv[tid] = v; si[tid] = idx;
                __syncthreads();
                v2 = sv[tid ^ j]; i2 = si[tid ^ j];
                __syncthreads();
            }
            // total order (val, idx): exact handling of duplicate values
            bool less  = (v < v2) || (v == v2 && idx < i2);
            bool lower = (tid & j) == 0;
            bool up    = (tid & k) == 0;   // k==512: final ascending merge
            if ((lower == up) != less) { v = v2; idx = i2; }
        }
    }

    wsVal[d * NCODE + tid] = v;
    wsIdx[d * NCODE + tid] = (unsigned short)idx;
}

// ================= kernel B: coalesced search + fused loss =================
// Block = 16 dims x 128 samples, 512 threads (16 dims x 32 rows x 4 elems).
__global__ __launch_bounds__(512)
void vq_search_loss(const float* __restrict__ enc,
                    const float* __restrict__ wsVal,
                    const unsigned short* __restrict__ wsIdx,
                    float* __restrict__ out,
                    float* __restrict__ wsLoss,
                    unsigned int* __restrict__ cnt)
{
    __shared__ float          cbv[DT][CBS];
    __shared__ unsigned short cbi[DT][CBS];
    __shared__ float red[8];
    __shared__ int   islast;

    const int tid   = threadIdx.x;
    const int bx    = blockIdx.x;
    const int dtile = bx & (NDIM / DT - 1);
    const int stile = bx >> 4;
    const int d0    = dtile * DT;
    const int n0    = stile * ST;

    // ---- stage sorted tables into LDS (coalesced) ----
    {
        const float4* src = reinterpret_cast<const float4*>(wsVal + d0 * NCODE);
        for (int i4 = tid; i4 < DT * NCODE / 4; i4 += 512) {
            float4 q = src[i4];
            int i = i4 * 4, dl2 = i >> 9, pos = i & (NCODE - 1);
            *reinterpret_cast<float4*>(&cbv[dl2][pos]) = q;
        }
        const uint2* srci = reinterpret_cast<const uint2*>(wsIdx + d0 * NCODE);
        for (int i4 = tid; i4 < DT * NCODE / 4; i4 += 512) {
            uint2 q = srci[i4];
            int i = i4 * 4, dl2 = i >> 9, pos = i & (NCODE - 1);
            *reinterpret_cast<uint2*>(&cbi[dl2][pos]) = q;
        }
    }
    __syncthreads();

    const int dl = tid & (DT - 1);
    const int rg = tid >> 4;               // 0..31
    const float*          vrow = cbv[dl];
    const unsigned short* irow = cbi[dl];

    float x[4]; int gi[4];
#pragma unroll
    for (int r = 0; r < 4; ++r) {
        int n = n0 + rg + 32 * r;
        gi[r] = n * NDIM + d0 + dl;
        x[r]  = enc[gi[r]];
    }

    // ---- 4 interleaved branchless binary searches: p = #(val < x) ----
    int p[4] = {0, 0, 0, 0};
#pragma unroll
    for (int s = NCODE / 2; s > 0; s >>= 1) {
#pragma unroll
        for (int r = 0; r < 4; ++r)
            if (vrow[p[r] + s - 1] < x[r]) p[r] += s;
    }

    float acc = 0.0f;
#pragma unroll
    for (int r = 0; r < 4; ++r) {
        int pp = p[r];
        if (vrow[pp] < x[r]) ++pp;          // count==512 fixup
        float d2l = FLT_MAX, d2r = FLT_MAX, vl = 0.0f, vr = 0.0f;
        int il = 0x7fffffff, ir = 0x7fffffff;
        if (pp > 0)     { vl = vrow[pp - 1]; il = irow[pp - 1]; float t = x[r] - vl; d2l = t * t; }
        if (pp < NCODE) { vr = vrow[pp];     ir = irow[pp];     float t = x[r] - vr; d2r = t * t; }
        out[gi[r]] = (d2l < d2r) ? vl : (d2r < d2l) ? vr : ((il < ir) ? vl : vr);
        acc += fminf(d2l, d2r);
    }

    // ---- block partial ----
#pragma unroll
    for (int off = 32; off > 0; off >>= 1)
        acc += __shfl_down(acc, off, 64);
    if ((tid & 63) == 0) red[tid >> 6] = acc;
    __syncthreads();

    if (tid == 0) {
        float s = 0.0f;
#pragma unroll
        for (int w = 0; w < 8; ++w) s += red[w];
        wsLoss[bx] = s;
        __threadfence();                               // publish partial
        unsigned int old = atomicAdd(cnt, 1u);         // device-scope
        islast = (old == (unsigned int)(NDIM - 1));
    }
    __syncthreads();

    // ---- last block: deterministic fixed-order reduce of 256 partials ----
    if (islast) {
        __threadfence();                               // acquire partials
        if (tid < NDIM) {
            const volatile float* wl = wsLoss;
            float a2 = wl[tid];
#pragma unroll
            for (int off = 32; off > 0; off >>= 1)
                a2 += __shfl_down(a2, off, 64);
            if ((tid & 63) == 0) red[tid >> 6] = a2;
        }
        __syncthreads();
        if (tid == 0)
            out[NSAMP * NDIM] = 2.0f * (red[0] + red[1] + red[2] + red[3]);
    }
}

extern "C" void kernel_launch(void* const* d_in, const int* in_sizes, int n_in,
                              void* d_out, int out_size, void* d_ws, size_t ws_size,
                              hipStream_t stream)
{
    const float* enc = (const float*)d_in[0];   // (2048, 256)
    const float* emb = (const float*)d_in[1];   // (1, 256, 512)
    float* out = (float*)d_out;                 // latent ++ loss

    char* ws = (char*)d_ws;
    unsigned int*   cnt    = (unsigned int*)(ws + WS_CNT_OFF);
    float*          wsLoss = (float*)(ws + WS_LOSS_OFF);
    float*          wsVal  = (float*)(ws + WS_VAL_OFF);
    unsigned short* wsIdx  = (unsigned short*)(ws + WS_IDX_OFF);

    vq_sort_init  <<<NDIM, 512, 0, stream>>>(emb, wsVal, wsIdx, cnt);
    vq_search_loss<<<(NSAMP / ST) * (NDIM / DT), 512, 0, stream>>>(enc, wsVal, wsIdx,
                                                                   out, wsLoss, cnt);
}

// Round 7
// 22.357 us; speedup vs baseline: 3.8190x; 1.1659x over previous
//
#include <hip/hip_runtime.h>
#include <hip/hip_bf16.h>
#include <float.h>

// VQ bottleneck, 2 dispatches, no atomics/fences/memsets (all measured slower).
// encoded: (2048, 256) f32, emb: (1, 256, 512) f32.
// out: latent (2048*256) f32 ++ loss (1) f32.
//
// Kernel 1: block b owns dim b entirely — bitonic sort (shfl for j<64 stages,
//   LDS for j>=64) keeps the sorted (val, original-idx) table in LDS, then 4
//   INTERLEAVED binary-search chains quantize all 2048 samples of column b.
//   No global table round-trip, no cross-block dependency.
// Kernel 2: 1-block deterministic reduce of the 256 loss partials.
//
// d2 = fl(fl(x-c)^2) is monotone in |x-c| per side => argmin is one of the two
// sorted-order neighbors of x; original indices reproduce np.argmin's
// first-index tie-break exactly (duplicate values / exact midpoints).

#define NSAMP 2048
#define NDIM  256
#define NCODE 512

__global__ __launch_bounds__(512)
void vq_fused(const float* __restrict__ enc,
              const float* __restrict__ emb,
              float* __restrict__ out,
              float* __restrict__ wsLoss)
{
    __shared__ float sv[NCODE];
    __shared__ int   si[NCODE];
    __shared__ float red[8];

    const int tid = threadIdx.x;
    const int b   = blockIdx.x;            // one block per dimension

    // ================= phase 1: bitonic sort of codebook dim b =================
    {
        float v  = emb[b * NCODE + tid];
        int  idx = tid;
        for (int k = 2; k <= NCODE; k <<= 1) {
            for (int j = k >> 1; j > 0; j >>= 1) {
                float v2; int i2;
                if (j < 64) {
                    v2 = __shfl_xor(v, j, 64);
                    i2 = __shfl_xor(idx, j, 64);
                } else {
                    sv[tid] = v; si[tid] = idx;
                    __syncthreads();
                    v2 = sv[tid ^ j]; i2 = si[tid ^ j];
                    __syncthreads();
                }
                // total order (val, idx): exact handling of duplicate values
                bool less  = (v < v2) || (v == v2 && idx < i2);
                bool lower = (tid & j) == 0;
                bool up    = (tid & k) == 0;   // k==512: final ascending merge
                if ((lower == up) != less) { v = v2; idx = i2; }
            }
        }
        sv[tid] = v;        // sorted table stays resident in LDS
        si[tid] = idx;
    }
    __syncthreads();

    // ========== phase 2: 4 interleaved binary-search chains (samples tid+512r) ==========
    float x[4];
#pragma unroll
    for (int r = 0; r < 4; ++r)
        x[r] = enc[(tid + 512 * r) * NDIM + b];

    int p[4] = {0, 0, 0, 0};
#pragma unroll
    for (int s = NCODE / 2; s > 0; s >>= 1) {
#pragma unroll
        for (int r = 0; r < 4; ++r)
            if (sv[p[r] + s - 1] < x[r]) p[r] += s;   // p = #(val < x), capped 511
    }

    float acc = 0.0f;
#pragma unroll
    for (int r = 0; r < 4; ++r) {
        int pp = p[r];
        if (sv[pp] < x[r]) ++pp;                      // count==512 fixup
        float d2l = FLT_MAX, d2r = FLT_MAX, vl = 0.0f, vr = 0.0f;
        int il = 0x7fffffff, ir = 0x7fffffff;
        if (pp > 0)     { vl = sv[pp - 1]; il = si[pp - 1]; float t = x[r] - vl; d2l = t * t; }
        if (pp < NCODE) { vr = sv[pp];     ir = si[pp];     float t = x[r] - vr; d2r = t * t; }
        out[(tid + 512 * r) * NDIM + b] =
            (d2l < d2r) ? vl : (d2r < d2l) ? vr : ((il < ir) ? vl : vr);
        acc += fminf(d2l, d2r);
    }

    // ================= phase 3: per-block loss partial =================
#pragma unroll
    for (int off = 32; off > 0; off >>= 1)
        acc += __shfl_down(acc, off, 64);
    if ((tid & 63) == 0) red[tid >> 6] = acc;
    __syncthreads();
    if (tid == 0) {
        float s = 0.0f;
#pragma unroll
        for (int w = 0; w < 8; ++w) s += red[w];
        wsLoss[b] = s;
    }
}

__global__ __launch_bounds__(256)
void vq_final(const float* __restrict__ wsLoss, float* __restrict__ out)
{
    __shared__ float red[4];
    const int tid = threadIdx.x;
    float acc = wsLoss[tid];               // 256 partials, fixed order
#pragma unroll
    for (int off = 32; off > 0; off >>= 1)
        acc += __shfl_down(acc, off, 64);
    if ((tid & 63) == 0) red[tid >> 6] = acc;
    __syncthreads();
    if (tid == 0)
        out[NSAMP * NDIM] = 2.0f * (red[0] + red[1] + red[2] + red[3]);
}

extern "C" void kernel_launch(void* const* d_in, const int* in_sizes, int n_in,
                              void* d_out, int out_size, void* d_ws, size_t ws_size,
                              hipStream_t stream)
{
    const float* enc = (const float*)d_in[0];   // (2048, 256)
    const float* emb = (const float*)d_in[1];   // (1, 256, 512)
    float* out = (float*)d_out;                 // latent ++ loss
    float* wsLoss = (float*)d_ws;               // 256 per-dim partials

    vq_fused<<<NDIM, 512, 0, stream>>>(enc, emb, out, wsLoss);
    vq_final<<<1, NDIM, 0, stream>>>(wsLoss, out);
}